// Round 4
// baseline (1803.288 us; speedup 1.0000x reference)
//
#include <hip/hip_runtime.h>
#include <hip/hip_bf16.h>

__device__ __forceinline__ unsigned int fkey(float f){
    unsigned int b = __float_as_uint(f);
    return (b & 0x80000000u) ? ~b : (b | 0x80000000u);
}
__device__ __forceinline__ float fdecode(unsigned int u){
    unsigned int b = (u & 0x80000000u) ? (u & 0x7FFFFFFFu) : ~u;
    return __uint_as_float(b);
}
__device__ __forceinline__ float eluf(float x){ return x > 0.f ? x : (expf(x) - 1.f); }
__device__ __forceinline__ float lrelu02(float x){ return x > 0.f ? x : 0.2f * x; }
__device__ __forceinline__ unsigned short f2bfbits(float f){
    __hip_bfloat16 h = __float2bfloat16(f);
    unsigned short u; __builtin_memcpy(&u, &h, 2); return u;
}
__device__ __forceinline__ float rawbf2f(unsigned int lo16){ return __uint_as_float(lo16 << 16); }

// edge-weight MLP (pure f32); returns w if mask (w>=0.2) else 0
__device__ __forceinline__ float edge_w(int u, int v,
    const float* __restrict__ nf, const float* __restrict__ coord,
    const float* __restrict__ fc1w, const float* __restrict__ fc1b,
    const float* __restrict__ fc2w, const float* __restrict__ fc2b)
{
    float f[10];
#pragma unroll
    for (int i = 0; i < 10; i++) f[i] = nf[(size_t)u * 10 + i];
    float ni = fc2b[0];
#pragma unroll
    for (int j = 0; j < 10; j++) {
        float h = fc1b[j];
#pragma unroll
        for (int i = 0; i < 10; i++) h += f[i] * fc1w[j * 10 + i];
        h = eluf(h);
        ni += h * fc2w[j];
    }
    float dx = coord[(size_t)u * 2]     - coord[(size_t)v * 2];
    float dy = coord[(size_t)u * 2 + 1] - coord[(size_t)v * 2 + 1];
    float gw = expf(-(dx * dx + dy * dy) * (1.0f / 1800.0f));
    float x = gw * (1.f + ni);
    float w = 0.1f + 1.9f / (1.f + expf(1.f - x));
    return (w >= 0.2f) ? w : 0.f;
}

__global__ void kzero(float* __restrict__ p, size_t n){
    size_t i = (size_t)blockIdx.x * blockDim.x + threadIdx.x;
    size_t stride = (size_t)gridDim.x * blockDim.x;
    for (; i < n; i += stride) p[i] = 0.f;
}

// K1: wave/node; xp (GAT proj) and xg (GCN proj) stored f32 in out+N ([N,128])
__global__ void __launch_bounds__(256) k1_node(
    const float* __restrict__ x_local, const float* __restrict__ x_global,
    const float* __restrict__ gat_w, const float* __restrict__ gcn_w,
    const float* __restrict__ att_src, const float* __restrict__ att_dst,
    float* __restrict__ xp,
    float* __restrict__ asv, float* __restrict__ adv,
    unsigned int* __restrict__ amax, float* __restrict__ deg, int N)
{
    int n = (blockIdx.x * blockDim.x + threadIdx.x) >> 6;
    int lane = threadIdx.x & 63;
    if (n >= N) return;
    float xl = x_local[(size_t)n * 64 + lane];
    float xg = x_global[(size_t)n * 64 + lane];
    float accA = 0.f, accG = 0.f;
    const float* wA = gat_w + lane * 64;
    const float* wG = gcn_w + lane * 64;
#pragma unroll 8
    for (int k = 0; k < 64; k++) {
        float xlk = __shfl(xl, k, 64);
        float xgk = __shfl(xg, k, 64);
        accA += xlk * wA[k];
        accG += xgk * wG[k];
    }
    xp[(size_t)n * 128 + lane]      = accA;
    xp[(size_t)n * 128 + 64 + lane] = accG;
    float va = accA * att_src[lane];
    float vd = accA * att_dst[lane];
#pragma unroll
    for (int o = 32; o; o >>= 1) {
        va += __shfl_xor(va, o, 64);
        vd += __shfl_xor(vd, o, 64);
    }
    if (lane == 0) {
        asv[n] = va; adv[n] = vd;
        amax[n] = fkey(lrelu02(va + vd));   // self-loop seed
        deg[n] = 1.0f;                       // self-loop weight
    }
}

// K2: thread/edge; w, deg & amax atomics
__global__ void __launch_bounds__(256) k2_edge(
    const int* __restrict__ ei,
    const float* __restrict__ nf, const float* __restrict__ coord,
    const float* __restrict__ fc1w, const float* __restrict__ fc1b,
    const float* __restrict__ fc2w, const float* __restrict__ fc2b,
    const float* __restrict__ asv, const float* __restrict__ adv,
    float* __restrict__ wgs, float* __restrict__ deg,
    unsigned int* __restrict__ amax, int E)
{
    int e = blockIdx.x * blockDim.x + threadIdx.x;
    if (e >= E) return;
    int u = ei[e], v = ei[E + e];
    float w = edge_w(u, v, nf, coord, fc1w, fc1b, fc2w, fc2b);
    if (wgs) wgs[e] = w;
    if (w > 0.f) {
        atomicAdd(&deg[v], w);
        atomicMax(&amax[v], fkey(lrelu02(asv[u] + adv[v])));
    }
}

// K3: thread/node; deg -> dinv in place, softmax denom seed
__global__ void __launch_bounds__(256) k3_node(
    const float* __restrict__ asv, const float* __restrict__ adv,
    float* __restrict__ degdinv, const unsigned int* __restrict__ amax,
    float* __restrict__ ssum, int N)
{
    int n = blockIdx.x * blockDim.x + threadIdx.x;
    if (n >= N) return;
    float d = degdinv[n];
    degdinv[n] = d > 0.f ? rsqrtf(fmaxf(d, 1e-12f)) : 0.f;
    float al = lrelu02(asv[n] + adv[n]);
    ssum[n] = expf(al - fdecode(amax[n]));
}

// K4: thread/edge; softmax denominator
template<bool RECOMP>
__global__ void __launch_bounds__(256) k4_denom(
    const int* __restrict__ ei, const float* __restrict__ wgs,
    const float* __restrict__ nf, const float* __restrict__ coord,
    const float* __restrict__ fc1w, const float* __restrict__ fc1b,
    const float* __restrict__ fc2w, const float* __restrict__ fc2b,
    const float* __restrict__ asv, const float* __restrict__ adv,
    const unsigned int* __restrict__ amax, float* __restrict__ ssum, int E)
{
    int e = blockIdx.x * blockDim.x + threadIdx.x;
    if (e >= E) return;
    int u = ei[e], v = ei[E + e];
    float w = RECOMP ? edge_w(u, v, nf, coord, fc1w, fc1b, fc2w, fc2b) : wgs[e];
    if (w <= 0.f) return;
    float a = lrelu02(asv[u] + adv[v]);
    atomicAdd(&ssum[v], expf(a - fdecode(amax[v])));
}

// K5 (f32 acc): wave/edge, lane=channel. BRANCH: 0=GAT, 1=GCN, 2=both
template<int BRANCH>
__global__ void __launch_bounds__(256) k5_f32(
    const int* __restrict__ ei, const float* __restrict__ wgs,
    const float* __restrict__ asv, const float* __restrict__ adv,
    const unsigned int* __restrict__ amax, const float* __restrict__ ssum,
    const float* __restrict__ dinv, const float* __restrict__ xp,
    float* __restrict__ accA, float* __restrict__ accG, int E)
{
    int e = (blockIdx.x * blockDim.x + threadIdx.x) >> 6;
    int lane = threadIdx.x & 63;
    if (e >= E) return;
    float w = wgs[e];
    if (w <= 0.f) return;
    int u = ei[e], v = ei[E + e];
    if (BRANCH == 0 || BRANCH == 2) {
        float a = lrelu02(asv[u] + adv[v]);
        float alpha = expf(a - fdecode(amax[v])) / (ssum[v] + 1e-16f);
        atomicAdd(&accA[(size_t)v * 64 + lane], alpha * xp[(size_t)u * 128 + lane]);
    }
    if (BRANCH == 1 || BRANCH == 2) {
        float nrm = dinv[u] * w * dinv[v];
        atomicAdd(&accG[(size_t)v * 64 + lane], nrm * xp[(size_t)u * 128 + 64 + lane]);
    }
}

// K5 (bf16-pair acc via CAS): wave = 2 edges x 32 channel-pairs (small-ws tiers)
template<int BRANCH, bool RECOMP>
__global__ void __launch_bounds__(256) k5_h2(
    const int* __restrict__ ei, const float* __restrict__ wgs,
    const float* __restrict__ nf, const float* __restrict__ coord,
    const float* __restrict__ fc1w, const float* __restrict__ fc1b,
    const float* __restrict__ fc2w, const float* __restrict__ fc2b,
    const float* __restrict__ asv, const float* __restrict__ adv,
    const unsigned int* __restrict__ amax, const float* __restrict__ ssum,
    const float* __restrict__ dinv, const float* __restrict__ xp,
    unsigned int* __restrict__ acc, int E)
{
    int wave = (blockIdx.x * blockDim.x + threadIdx.x) >> 6;
    int lane = threadIdx.x & 63;
    int e = wave * 2 + (lane >> 5);
    int l = lane & 31;
    if (e >= E) return;
    int u = ei[e], v = ei[E + e];
    float w = RECOMP ? edge_w(u, v, nf, coord, fc1w, fc1b, fc2w, fc2b) : wgs[e];
    if (w <= 0.f) return;
    float s;
    if (BRANCH == 0) {
        float a = lrelu02(asv[u] + adv[v]);
        s = expf(a - fdecode(amax[v])) / (ssum[v] + 1e-16f);
    } else {
        s = dinv[u] * w * dinv[v];
    }
    size_t base = (size_t)u * 128 + (BRANCH == 1 ? 64 : 0) + 2 * l;
    float x0 = s * xp[base];
    float x1 = s * xp[base + 1];
    unsigned int* addr = &acc[(size_t)v * 32 + l];
    unsigned int cur = *(volatile unsigned int*)addr, prev;
    do {
        prev = cur;
        float c0 = rawbf2f(prev & 0xffffu) + x0;
        float c1 = rawbf2f(prev >> 16) + x1;
        unsigned int nv = (unsigned int)f2bfbits(c0) | ((unsigned int)f2bfbits(c1) << 16);
        cur = atomicCAS(addr, prev, nv);
    } while (cur != prev);
}

// K6a: GAT epilogue; writes xl over xp GAT slot; optional acc re-zero
template<int ACCM, bool ZERO>
__global__ void __launch_bounds__(256) k6a_gat(
    const float* __restrict__ asv, const float* __restrict__ adv,
    const unsigned int* __restrict__ amax, const float* __restrict__ ssum,
    void* __restrict__ accv, const float* __restrict__ gat_b,
    float* __restrict__ out, int N)
{
    int n = (blockIdx.x * blockDim.x + threadIdx.x) >> 6;
    int lane = threadIdx.x & 63;
    if (n >= N) return;
    float av;
    if (ACCM == 0) av = ((float*)accv)[(size_t)n * 64 + lane];
    else {
        unsigned int wb = ((unsigned int*)accv)[(size_t)n * 32 + (lane >> 1)];
        av = (lane & 1) ? rawbf2f(wb >> 16) : rawbf2f(wb & 0xffffu);
    }
    float al = lrelu02(asv[n] + adv[n]);
    float alpha_l = expf(al - fdecode(amax[n])) / (ssum[n] + 1e-16f);
    float* xp = out + N;
    float xl = eluf(av + alpha_l * xp[(size_t)n * 128 + lane] + gat_b[lane]);
    xp[(size_t)n * 128 + lane] = xl;
    if (ZERO) {
        if (ACCM == 0) ((float*)accv)[(size_t)n * 64 + lane] = 0.f;
        else if ((lane & 1) == 0) ((unsigned int*)accv)[(size_t)n * 32 + (lane >> 1)] = 0u;
    }
}

// K6b: GCN epilogue + fuse MLP + pred
template<int ACCM>
__global__ void __launch_bounds__(256) k6b_gcn_fuse(
    const float* __restrict__ dinv, const void* __restrict__ accv,
    const float* __restrict__ gcn_b,
    const float* __restrict__ fuse_w1, const float* __restrict__ fuse_b1,
    const float* __restrict__ fuse_w2, const float* __restrict__ fuse_b2,
    float* __restrict__ out, int N)
{
    __shared__ float cat_lds[4][128];
    int wv = threadIdx.x >> 6;
    int lane = threadIdx.x & 63;
    int n = blockIdx.x * 4 + wv;
    float* xp = out + N;
    if (n < N) {
        float av;
        if (ACCM == 0) av = ((const float*)accv)[(size_t)n * 64 + lane];
        else {
            unsigned int wb = ((const unsigned int*)accv)[(size_t)n * 32 + (lane >> 1)];
            av = (lane & 1) ? rawbf2f(wb >> 16) : rawbf2f(wb & 0xffffu);
        }
        float dv = dinv[n];
        float c = av + dv * dv * xp[(size_t)n * 128 + 64 + lane] + gcn_b[lane];
        float xg = c > 0.f ? c : 0.f;
        float xl = xp[(size_t)n * 128 + lane];
        xp[(size_t)n * 128 + 64 + lane] = xg;
        cat_lds[wv][lane] = xl;
        cat_lds[wv][64 + lane] = xg;
    }
    __syncthreads();
    if (n < N) {
        float acc = fuse_b1[lane];
        const float* wrow = fuse_w1 + lane * 128;
#pragma unroll 8
        for (int k = 0; k < 128; k++) acc += cat_lds[wv][k] * wrow[k];
        float hf = acc > 0.f ? acc : 0.f;
        float p = hf * fuse_w2[lane];
#pragma unroll
        for (int o = 32; o; o >>= 1) p += __shfl_xor(p, o, 64);
        if (lane == 0) out[n] = p + fuse_b2[0];
    }
}

extern "C" void kernel_launch(void* const* d_in, const int* in_sizes, int n_in,
                              void* d_out, int out_size, void* d_ws, size_t ws_size,
                              hipStream_t stream) {
    const float* x_local  = (const float*)d_in[0];
    const float* x_global = (const float*)d_in[1];
    const float* noise_f  = (const float*)d_in[2];
    const float* coord    = (const float*)d_in[3];
    const int*   ei       = (const int*)d_in[4];
    const float* fc1_w    = (const float*)d_in[5];
    const float* fc1_b    = (const float*)d_in[6];
    const float* fc2_w    = (const float*)d_in[7];
    const float* fc2_b    = (const float*)d_in[8];
    const float* gat_w    = (const float*)d_in[9];
    const float* gat_b    = (const float*)d_in[10];
    const float* att_src  = (const float*)d_in[11];
    const float* att_dst  = (const float*)d_in[12];
    const float* gcn_w    = (const float*)d_in[13];
    const float* gcn_b    = (const float*)d_in[14];
    const float* fuse_w1  = (const float*)d_in[15];
    const float* fuse_b1  = (const float*)d_in[16];
    const float* fuse_w2  = (const float*)d_in[17];
    const float* fuse_b2  = (const float*)d_in[18];
    float* out = (float*)d_out;

    const int N = out_size / 129;        // pred [N] + cat [N,128]
    const int E = in_sizes[4] / 2;

    auto rup = [](size_t b) { return (b + 255) & ~(size_t)255; };
    size_t scal = rup((size_t)N * 4);
    size_t SC   = 5 * scal;
    size_t WG   = rup((size_t)E * 4);
    size_t ACCF = rup((size_t)N * 64 * 4);
    size_t ACCH = rup((size_t)N * 32 * 4);

    int tier;
    if      (ws_size >= SC + WG + 2 * ACCF) tier = 0;
    else if (ws_size >= SC + WG + ACCF)     tier = 1;
    else if (ws_size >= SC + WG + ACCH)     tier = 2;
    else                                    tier = 3;

    char* p = (char*)d_ws;
    float* asv = (float*)p; p += scal;
    float* adv = (float*)p; p += scal;
    float* deg = (float*)p; p += scal;             // becomes dinv in K3
    unsigned int* amax = (unsigned int*)p; p += scal;
    float* ssum = (float*)p; p += scal;
    float* wgs = nullptr;
    if (tier < 3) { wgs = (float*)p; p += WG; }
    float* accA = nullptr; float* accG = nullptr; unsigned int* acch = nullptr;
    if (tier == 0)      { accA = (float*)p; p += ACCF; accG = (float*)p; p += ACCF; }
    else if (tier == 1) { accA = (float*)p; p += ACCF; accG = accA; }
    else                { acch = (unsigned int*)p; p += ACCH; }

    float* xp = out + N;   // [N,128] f32 projections -> final cat (in place)

    dim3 blk(256);
    int bn_wave = (N + 3) / 4;
    int be      = (E + 255) / 256;
    int bn      = (N + 255) / 256;
    int bew     = (E + 3) / 4;
    int bew2    = (E + 7) / 8;

    if (tier == 0) {
        kzero<<<2048, blk, 0, stream>>>(accA, (size_t)N * 64);
        kzero<<<2048, blk, 0, stream>>>(accG, (size_t)N * 64);
    } else if (tier == 1) {
        kzero<<<2048, blk, 0, stream>>>(accA, (size_t)N * 64);
    } else {
        kzero<<<2048, blk, 0, stream>>>((float*)acch, (size_t)N * 32);
    }

    k1_node<<<bn_wave, blk, 0, stream>>>(x_local, x_global, gat_w, gcn_w,
        att_src, att_dst, xp, asv, adv, amax, deg, N);

    k2_edge<<<be, blk, 0, stream>>>(ei, noise_f, coord, fc1_w, fc1_b, fc2_w, fc2_b,
        asv, adv, wgs, deg, amax, E);

    k3_node<<<bn, blk, 0, stream>>>(asv, adv, deg, amax, ssum, N);

    if (tier < 3)
        k4_denom<false><<<be, blk, 0, stream>>>(ei, wgs, noise_f, coord,
            fc1_w, fc1_b, fc2_w, fc2_b, asv, adv, amax, ssum, E);
    else
        k4_denom<true><<<be, blk, 0, stream>>>(ei, wgs, noise_f, coord,
            fc1_w, fc1_b, fc2_w, fc2_b, asv, adv, amax, ssum, E);

    if (tier == 0) {
        k5_f32<2><<<bew, blk, 0, stream>>>(ei, wgs, asv, adv, amax, ssum, deg, xp, accA, accG, E);
        k6a_gat<0, false><<<bn_wave, blk, 0, stream>>>(asv, adv, amax, ssum, accA, gat_b, out, N);
        k6b_gcn_fuse<0><<<bn_wave, blk, 0, stream>>>(deg, accG, gcn_b,
            fuse_w1, fuse_b1, fuse_w2, fuse_b2, out, N);
    } else if (tier == 1) {
        k5_f32<0><<<bew, blk, 0, stream>>>(ei, wgs, asv, adv, amax, ssum, deg, xp, accA, accA, E);
        k6a_gat<0, true><<<bn_wave, blk, 0, stream>>>(asv, adv, amax, ssum, accA, gat_b, out, N);
        k5_f32<1><<<bew, blk, 0, stream>>>(ei, wgs, asv, adv, amax, ssum, deg, xp, accA, accA, E);
        k6b_gcn_fuse<0><<<bn_wave, blk, 0, stream>>>(deg, accA, gcn_b,
            fuse_w1, fuse_b1, fuse_w2, fuse_b2, out, N);
    } else if (tier == 2) {
        k5_h2<0, false><<<bew2, blk, 0, stream>>>(ei, wgs, noise_f, coord,
            fc1_w, fc1_b, fc2_w, fc2_b, asv, adv, amax, ssum, deg, xp, acch, E);
        k6a_gat<1, true><<<bn_wave, blk, 0, stream>>>(asv, adv, amax, ssum, acch, gat_b, out, N);
        k5_h2<1, false><<<bew2, blk, 0, stream>>>(ei, wgs, noise_f, coord,
            fc1_w, fc1_b, fc2_w, fc2_b, asv, adv, amax, ssum, deg, xp, acch, E);
        k6b_gcn_fuse<1><<<bn_wave, blk, 0, stream>>>(deg, acch, gcn_b,
            fuse_w1, fuse_b1, fuse_w2, fuse_b2, out, N);
    } else {
        k5_h2<0, true><<<bew2, blk, 0, stream>>>(ei, wgs, noise_f, coord,
            fc1_w, fc1_b, fc2_w, fc2_b, asv, adv, amax, ssum, deg, xp, acch, E);
        k6a_gat<1, true><<<bn_wave, blk, 0, stream>>>(asv, adv, amax, ssum, acch, gat_b, out, N);
        k5_h2<1, true><<<bew2, blk, 0, stream>>>(ei, wgs, noise_f, coord,
            fc1_w, fc1_b, fc2_w, fc2_b, asv, adv, amax, ssum, deg, xp, acch, E);
        k6b_gcn_fuse<1><<<bn_wave, blk, 0, stream>>>(deg, acch, gcn_b,
            fuse_w1, fuse_b1, fuse_w2, fuse_b2, out, N);
    }
}

// Round 5
// 1263.990 us; speedup vs baseline: 1.4267x; 1.4267x over previous
//
#include <hip/hip_runtime.h>
#include <hip/hip_bf16.h>

typedef __hip_bfloat16 bf16;

__device__ __forceinline__ float eluf(float x){ return x > 0.f ? x : (expf(x) - 1.f); }
__device__ __forceinline__ float lrelu02(float x){ return x > 0.f ? x : 0.2f * x; }

// edge-weight MLP (pure f32); returns w if mask (w>=0.2) else 0
__device__ __forceinline__ float edge_w(int u, int v,
    const float* __restrict__ nf, const float* __restrict__ coord,
    const float* __restrict__ fc1w, const float* __restrict__ fc1b,
    const float* __restrict__ fc2w, const float* __restrict__ fc2b)
{
    float f[10];
#pragma unroll
    for (int i = 0; i < 10; i++) f[i] = nf[(size_t)u * 10 + i];
    float ni = fc2b[0];
#pragma unroll
    for (int j = 0; j < 10; j++) {
        float h = fc1b[j];
#pragma unroll
        for (int i = 0; i < 10; i++) h += f[i] * fc1w[j * 10 + i];
        h = eluf(h);
        ni += h * fc2w[j];
    }
    float dx = coord[(size_t)u * 2]     - coord[(size_t)v * 2];
    float dy = coord[(size_t)u * 2 + 1] - coord[(size_t)v * 2 + 1];
    float gw = expf(-(dx * dx + dy * dy) * (1.0f / 1800.0f));
    float x = gw * (1.f + ni);
    float w = 0.1f + 1.9f / (1.f + expf(1.f - x));
    return (w >= 0.2f) ? w : 0.f;
}

__global__ void kzero_u32(unsigned int* __restrict__ p, size_t n){
    size_t i = (size_t)blockIdx.x * blockDim.x + threadIdx.x;
    size_t stride = (size_t)gridDim.x * blockDim.x;
    for (; i < n; i += stride) p[i] = 0u;
}

// K1: wave/node; xp (GAT proj || GCN proj) stored bf16 in ws [N,128]
__global__ void __launch_bounds__(256) k1_node(
    const float* __restrict__ x_local, const float* __restrict__ x_global,
    const float* __restrict__ gat_w, const float* __restrict__ gcn_w,
    const float* __restrict__ att_src, const float* __restrict__ att_dst,
    bf16* __restrict__ xp,
    float* __restrict__ asv, float* __restrict__ adv,
    float* __restrict__ deg, int N)
{
    int n = (blockIdx.x * blockDim.x + threadIdx.x) >> 6;
    int lane = threadIdx.x & 63;
    if (n >= N) return;
    float xl = x_local[(size_t)n * 64 + lane];
    float xg = x_global[(size_t)n * 64 + lane];
    float accA = 0.f, accG = 0.f;
    const float* wA = gat_w + lane * 64;
    const float* wG = gcn_w + lane * 64;
#pragma unroll 8
    for (int k = 0; k < 64; k++) {
        float xlk = __shfl(xl, k, 64);
        float xgk = __shfl(xg, k, 64);
        accA += xlk * wA[k];
        accG += xgk * wG[k];
    }
    xp[(size_t)n * 128 + lane]      = __float2bfloat16(accA);
    xp[(size_t)n * 128 + 64 + lane] = __float2bfloat16(accG);
    float va = accA * att_src[lane];
    float vd = accA * att_dst[lane];
#pragma unroll
    for (int o = 32; o; o >>= 1) {
        va += __shfl_xor(va, o, 64);
        vd += __shfl_xor(vd, o, 64);
    }
    if (lane == 0) {
        asv[n] = va; adv[n] = vd;
        deg[n] = 1.0f;             // self-loop weight
    }
}

// K2a: thread/edge; edge MLP -> wg_e, count valid edges per dst, deg sum
__global__ void __launch_bounds__(256) k2a_edge(
    const int* __restrict__ ei,
    const float* __restrict__ nf, const float* __restrict__ coord,
    const float* __restrict__ fc1w, const float* __restrict__ fc1b,
    const float* __restrict__ fc2w, const float* __restrict__ fc2b,
    float* __restrict__ wg_e, unsigned int* __restrict__ counts,
    float* __restrict__ deg, int E)
{
    int e = blockIdx.x * blockDim.x + threadIdx.x;
    if (e >= E) return;
    int u = ei[e], v = ei[E + e];
    float w = edge_w(u, v, nf, coord, fc1w, fc1b, fc2w, fc2b);
    wg_e[e] = w;
    if (w > 0.f) {
        atomicAdd(&counts[v], 1u);
        atomicAdd(&deg[v], w);
    }
}

// Kscan: single-block exclusive scan of counts -> offs[0..N]
__global__ void __launch_bounds__(1024) kscan(
    const unsigned int* __restrict__ counts, int* __restrict__ offs, int N)
{
    __shared__ int wsum[16];
    int tid = threadIdx.x;
    int lane = tid & 63, wv = tid >> 6;
    if (tid == 0) offs[0] = 0;
    int carry = 0;
    for (int base = 0; base < N; base += 1024) {
        int i = base + tid;
        int x = (i < N) ? (int)counts[i] : 0;
        int vincl = x;
#pragma unroll
        for (int o = 1; o < 64; o <<= 1) {
            int t = __shfl_up(vincl, o, 64);
            if (lane >= o) vincl += t;
        }
        if (lane == 63) wsum[wv] = vincl;
        __syncthreads();
        if (wv == 0 && lane < 16) {
            int s = wsum[lane];
#pragma unroll
            for (int o = 1; o < 16; o <<= 1) {
                int t = __shfl_up(s, o, 16);
                if (lane >= o) s += t;
            }
            wsum[lane] = s;   // inclusive wave-sum scan
        }
        __syncthreads();
        int wprefix = (wv > 0) ? wsum[wv - 1] : 0;
        int tot = wsum[15];
        if (i < N) offs[i + 1] = carry + wprefix + vincl;
        carry += tot;
        __syncthreads();   // wsum reused next iteration
    }
}

// Kdinv: thread/node; deg -> dinv in place (deg >= 1 always)
__global__ void __launch_bounds__(256) kdinv(float* __restrict__ deg, int N)
{
    int n = blockIdx.x * blockDim.x + threadIdx.x;
    if (n >= N) return;
    deg[n] = rsqrtf(fmaxf(deg[n], 1e-12f));
}

// K2c: thread/edge; scatter valid edges (u, w) into dst-CSR slots
__global__ void __launch_bounds__(256) k2c_scatter(
    const int* __restrict__ ei, const float* __restrict__ wg_e,
    const int* __restrict__ offs, unsigned int* __restrict__ cursor,
    int2* __restrict__ csr, int E)
{
    int e = blockIdx.x * blockDim.x + threadIdx.x;
    if (e >= E) return;
    float w = wg_e[e];
    if (w <= 0.f) return;
    int u = ei[e], v = ei[E + e];
    int pos = offs[v] + (int)atomicAdd(&cursor[v], 1u);
    int2 val;
    val.x = u;
    val.y = __float_as_int(w);
    csr[pos] = val;
}

// K3: wave per dst node. Online-softmax GAT + weighted GCN + epilogue + fuse MLP.
__global__ void __launch_bounds__(256) k3_gather(
    const int* __restrict__ offs, const int2* __restrict__ csr,
    const float* __restrict__ asv, const float* __restrict__ adv,
    const float* __restrict__ dinv, const bf16* __restrict__ xp,
    const float* __restrict__ gat_b, const float* __restrict__ gcn_b,
    const float* __restrict__ fw1, const float* __restrict__ fb1,
    const float* __restrict__ fw2, const float* __restrict__ fb2,
    float* __restrict__ out, int N)
{
    __shared__ float cat_lds[4][128];
    int wv = threadIdx.x >> 6;
    int lane = threadIdx.x & 63;
    int v = blockIdx.x * 4 + wv;
    if (v >= N) return;

    int beg = offs[v], end = offs[v + 1];
    float adv_v = adv[v];
    float dinv_v = dinv[v];
    float a_l = lrelu02(asv[v] + adv_v);     // self-loop logit
    float m = a_l, s = 1.f;                   // online softmax state (self seeds)
    float accA = 0.f, accG = 0.f;

    for (int base = beg; base < end; base += 64) {
        int i = base + lane;
        bool has = i < end;
        int2 ew = has ? csr[i] : make_int2(0, 0);
        int u = ew.x;
        float w = __int_as_float(ew.y);
        float a = has ? lrelu02(asv[u] + adv_v) : -3e38f;
        // chunk max + rescale
        float mc = a;
#pragma unroll
        for (int o = 32; o; o >>= 1) mc = fmaxf(mc, __shfl_xor(mc, o, 64));
        if (mc > m) {
            float r = expf(m - mc);
            s *= r; accA *= r; m = mc;
        }
        float p = has ? expf(a - m) : 0.f;
        float ps = p;
#pragma unroll
        for (int o = 32; o; o >>= 1) ps += __shfl_xor(ps, o, 64);
        s += ps;
        float nrm = has ? (dinv[u] * w * dinv_v) : 0.f;
        int cnt = end - base; if (cnt > 64) cnt = 64;
        for (int j = 0; j < cnt; j++) {
            float pj = __shfl(p, j, 64);
            float nj = __shfl(nrm, j, 64);
            int  uj = __shfl(u, j, 64);
            const bf16* row = xp + (size_t)uj * 128;
            accA += pj * __bfloat162float(row[lane]);
            accG += nj * __bfloat162float(row[64 + lane]);
        }
    }
    // self-loop contributions
    const bf16* rowv = xp + (size_t)v * 128;
    accA += expf(a_l - m) * __bfloat162float(rowv[lane]);
    accG += dinv_v * dinv_v * __bfloat162float(rowv[64 + lane]);

    float xl = eluf(accA / (s + 1e-16f) + gat_b[lane]);
    float c = accG + gcn_b[lane];
    float xg = c > 0.f ? c : 0.f;
    out[(size_t)N + (size_t)v * 128 + lane]      = xl;
    out[(size_t)N + (size_t)v * 128 + 64 + lane] = xg;
    cat_lds[wv][lane] = xl;
    cat_lds[wv][64 + lane] = xg;
    // same-wave LDS read (no barrier needed): fuse MLP
    float acc = fb1[lane];
    const float* wrow = fw1 + lane * 128;
#pragma unroll 8
    for (int k = 0; k < 128; k++) acc += cat_lds[wv][k] * wrow[k];
    float hf = acc > 0.f ? acc : 0.f;
    float p = hf * fw2[lane];
#pragma unroll
    for (int o = 32; o; o >>= 1) p += __shfl_xor(p, o, 64);
    if (lane == 0) out[v] = p + fb2[0];
}

extern "C" void kernel_launch(void* const* d_in, const int* in_sizes, int n_in,
                              void* d_out, int out_size, void* d_ws, size_t ws_size,
                              hipStream_t stream) {
    const float* x_local  = (const float*)d_in[0];
    const float* x_global = (const float*)d_in[1];
    const float* noise_f  = (const float*)d_in[2];
    const float* coord    = (const float*)d_in[3];
    const int*   ei       = (const int*)d_in[4];
    const float* fc1_w    = (const float*)d_in[5];
    const float* fc1_b    = (const float*)d_in[6];
    const float* fc2_w    = (const float*)d_in[7];
    const float* fc2_b    = (const float*)d_in[8];
    const float* gat_w    = (const float*)d_in[9];
    const float* gat_b    = (const float*)d_in[10];
    const float* att_src  = (const float*)d_in[11];
    const float* att_dst  = (const float*)d_in[12];
    const float* gcn_w    = (const float*)d_in[13];
    const float* gcn_b    = (const float*)d_in[14];
    const float* fuse_w1  = (const float*)d_in[15];
    const float* fuse_b1  = (const float*)d_in[16];
    const float* fuse_w2  = (const float*)d_in[17];
    const float* fuse_b2  = (const float*)d_in[18];
    float* out = (float*)d_out;

    const int N = out_size / 129;        // pred [N] + cat [N,128]
    const int E = in_sizes[4] / 2;

    auto rup = [](size_t b) { return (b + 255) & ~(size_t)255; };
    char* p = (char*)d_ws;
    auto carve = [&](size_t bytes) { char* q = p; p += rup(bytes); return (void*)q; };

    unsigned int* counts = (unsigned int*)carve((size_t)N * 4);
    unsigned int* cursor = (unsigned int*)carve((size_t)N * 4);   // adjacent to counts
    int*   offs  = (int*)  carve(((size_t)N + 1) * 4);
    float* deg   = (float*)carve((size_t)N * 4);                  // -> dinv in place
    float* asv   = (float*)carve((size_t)N * 4);
    float* adv   = (float*)carve((size_t)N * 4);
    float* wg_e  = (float*)carve((size_t)E * 4);                  // 6.4 MB
    int2*  csr   = (int2*) carve((size_t)E * 8);                  // 12.8 MB
    bf16*  xp    = (bf16*) carve((size_t)N * 128 * 2);            // 25.6 MB

    dim3 blk(256);
    int bn_wave = (N + 3) / 4;
    int be      = (E + 255) / 256;
    int bn      = (N + 255) / 256;

    // counts + cursor are adjacent: zero both in one pass (2N + pad u32s)
    kzero_u32<<<512, blk, 0, stream>>>(counts, ((size_t)rup((size_t)N*4) * 2) / 4);

    k1_node<<<bn_wave, blk, 0, stream>>>(x_local, x_global, gat_w, gcn_w,
        att_src, att_dst, xp, asv, adv, deg, N);

    k2a_edge<<<be, blk, 0, stream>>>(ei, noise_f, coord,
        fc1_w, fc1_b, fc2_w, fc2_b, wg_e, counts, deg, E);

    kscan<<<1, 1024, 0, stream>>>(counts, offs, N);

    kdinv<<<bn, blk, 0, stream>>>(deg, N);

    k2c_scatter<<<be, blk, 0, stream>>>(ei, wg_e, offs, cursor, csr, E);

    k3_gather<<<bn_wave, blk, 0, stream>>>(offs, csr, asv, adv, deg, xp,
        gat_b, gcn_b, fuse_w1, fuse_b1, fuse_w2, fuse_b2, out, N);
}

// Round 6
// 1212.823 us; speedup vs baseline: 1.4869x; 1.0422x over previous
//
#include <hip/hip_runtime.h>
#include <hip/hip_bf16.h>

typedef __hip_bfloat16 bf16;

__device__ __forceinline__ float eluf(float x){ return x > 0.f ? x : (expf(x) - 1.f); }
__device__ __forceinline__ float lrelu02(float x){ return x > 0.f ? x : 0.2f * x; }

__global__ void kzero_u32(unsigned int* __restrict__ p, size_t n){
    size_t i = (size_t)blockIdx.x * blockDim.x + threadIdx.x;
    size_t stride = (size_t)gridDim.x * blockDim.x;
    for (; i < n; i += stride) p[i] = 0u;
}

// K12: fused node-transform + edge-MLP. Blocks [0,NBn): wave/node; rest: thread/edge.
__global__ void __launch_bounds__(256) k12(
    const float* __restrict__ x_local, const float* __restrict__ x_global,
    const float* __restrict__ gat_w, const float* __restrict__ gcn_w,
    const float* __restrict__ att_src, const float* __restrict__ att_dst,
    bf16* __restrict__ xp, float* __restrict__ asv, float* __restrict__ adv,
    const int* __restrict__ ei,
    const float* __restrict__ nf, const float* __restrict__ coord,
    const float* __restrict__ fc1w, const float* __restrict__ fc1b,
    const float* __restrict__ fc2w, const float* __restrict__ fc2b,
    float* __restrict__ wg_e, unsigned int* __restrict__ counts,
    float* __restrict__ deg,   // edge-weight sums only (self +1 added in kdinv)
    int NBn, int N, int E)
{
    if ((int)blockIdx.x < NBn) {
        // ---- node path: xp projections + attention scalars ----
        int n = (blockIdx.x * blockDim.x + threadIdx.x) >> 6;
        int lane = threadIdx.x & 63;
        if (n >= N) return;
        float xl = x_local[(size_t)n * 64 + lane];
        float xg = x_global[(size_t)n * 64 + lane];
        float accA = 0.f, accG = 0.f;
        const float* wA = gat_w + lane * 64;
        const float* wG = gcn_w + lane * 64;
#pragma unroll 8
        for (int k = 0; k < 64; k++) {
            float xlk = __shfl(xl, k, 64);
            float xgk = __shfl(xg, k, 64);
            accA += xlk * wA[k];
            accG += xgk * wG[k];
        }
        xp[(size_t)n * 128 + lane]      = __float2bfloat16(accA);
        xp[(size_t)n * 128 + 64 + lane] = __float2bfloat16(accG);
        float va = accA * att_src[lane];
        float vd = accA * att_dst[lane];
#pragma unroll
        for (int o = 32; o; o >>= 1) {
            va += __shfl_xor(va, o, 64);
            vd += __shfl_xor(vd, o, 64);
        }
        if (lane == 0) { asv[n] = va; adv[n] = vd; }
    } else {
        // ---- edge path: weight MLP + counts/deg atomics ----
        int e = ((int)blockIdx.x - NBn) * (int)blockDim.x + (int)threadIdx.x;
        if (e >= E) return;
        int u = ei[e], v = ei[E + e];
        float f[10];
#pragma unroll
        for (int i = 0; i < 10; i++) f[i] = nf[(size_t)u * 10 + i];
        float ni = fc2b[0];
#pragma unroll
        for (int j = 0; j < 10; j++) {
            float h = fc1b[j];
#pragma unroll
            for (int i = 0; i < 10; i++) h += f[i] * fc1w[j * 10 + i];
            h = eluf(h);
            ni += h * fc2w[j];
        }
        float dx = coord[(size_t)u * 2]     - coord[(size_t)v * 2];
        float dy = coord[(size_t)u * 2 + 1] - coord[(size_t)v * 2 + 1];
        float gw = expf(-(dx * dx + dy * dy) * (1.0f / 1800.0f));
        float x = gw * (1.f + ni);
        float w = 0.1f + 1.9f / (1.f + expf(1.f - x));
        w = (w >= 0.2f) ? w : 0.f;
        wg_e[e] = w;
        if (w > 0.f) {
            atomicAdd(&counts[v], 1u);
            atomicAdd(&deg[v], w);
        }
    }
}

// Kscan: single-block exclusive scan, 4 elements/thread
__global__ void __launch_bounds__(1024) kscan(
    const unsigned int* __restrict__ counts, int* __restrict__ offs, int N)
{
    __shared__ int wsum[16];
    int tid = threadIdx.x;
    int lane = tid & 63, wv = tid >> 6;
    int carry = 0;
    for (int base = 0; base < N; base += 4096) {
        int i0 = base + tid * 4;
        uint4 c = make_uint4(0u, 0u, 0u, 0u);
        if (i0 + 3 < N) c = *(const uint4*)(counts + i0);
        else {
            if (i0 + 0 < N) c.x = counts[i0];
            if (i0 + 1 < N) c.y = counts[i0 + 1];
            if (i0 + 2 < N) c.z = counts[i0 + 2];
            if (i0 + 3 < N) c.w = counts[i0 + 3];
        }
        int t0 = (int)c.x, t1 = t0 + (int)c.y, t2 = t1 + (int)c.z, tot = t2 + (int)c.w;
        int incl = tot;
#pragma unroll
        for (int o = 1; o < 64; o <<= 1) {
            int tt = __shfl_up(incl, o, 64);
            if (lane >= o) incl += tt;
        }
        if (lane == 63) wsum[wv] = incl;
        __syncthreads();
        if (wv == 0 && lane < 16) {
            int s2 = wsum[lane];
#pragma unroll
            for (int o = 1; o < 16; o <<= 1) {
                int tt = __shfl_up(s2, o, 16);
                if (lane >= o) s2 += tt;
            }
            wsum[lane] = s2;
        }
        __syncthreads();
        int wpre = (wv > 0) ? wsum[wv - 1] : 0;
        int excl = carry + wpre + (incl - tot);
        int4 o4 = make_int4(excl, excl + t0, excl + t1, excl + t2);
        if (i0 + 3 < N) *(int4*)(offs + i0) = o4;
        else {
            if (i0 + 0 < N) offs[i0]     = o4.x;
            if (i0 + 1 < N) offs[i0 + 1] = o4.y;
            if (i0 + 2 < N) offs[i0 + 2] = o4.z;
            if (i0 + 3 < N) offs[i0 + 3] = o4.w;
        }
        carry += wsum[15];
        __syncthreads();
    }
    if (tid == 0) offs[N] = carry;
}

// Kdinv: deg(edge sums) + 1(self) -> dinv in place
__global__ void __launch_bounds__(256) kdinv(float* __restrict__ deg, int N)
{
    int n = blockIdx.x * blockDim.x + threadIdx.x;
    if (n >= N) return;
    deg[n] = rsqrtf(deg[n] + 1.0f);
}

// K2c: scatter valid edges (u, w) into dst-CSR slots
__global__ void __launch_bounds__(256) k2c_scatter(
    const int* __restrict__ ei, const float* __restrict__ wg_e,
    const int* __restrict__ offs, unsigned int* __restrict__ cursor,
    int2* __restrict__ csr, int E)
{
    int e = blockIdx.x * blockDim.x + threadIdx.x;
    if (e >= E) return;
    float w = wg_e[e];
    if (w <= 0.f) return;
    int u = ei[e], v = ei[E + e];
    int pos = offs[v] + (int)atomicAdd(&cursor[v], 1u);
    int2 val;
    val.x = u;
    val.y = __float_as_int(w);
    csr[pos] = val;
}

// K3: wave per dst node. 16 lanes/edge, 16B xp loads, 4 edges/step.
__global__ void __launch_bounds__(256) k3_gather(
    const int* __restrict__ offs, const int2* __restrict__ csr,
    const float* __restrict__ asv, const float* __restrict__ adv,
    const float* __restrict__ dinv, const bf16* __restrict__ xp,
    const float* __restrict__ gat_b, const float* __restrict__ gcn_b,
    const float* __restrict__ fw1, const float* __restrict__ fb1,
    const float* __restrict__ fw2, const float* __restrict__ fb2,
    float* __restrict__ out, int N)
{
    __shared__ float cat_lds[4][128];
    int wv = threadIdx.x >> 6;
    int lane = threadIdx.x & 63;
    int v = blockIdx.x * 4 + wv;
    if (v >= N) return;

    int t = lane & 15;        // 16B-slot within row (t<8: GAT chans, t>=8: GCN)
    int g = lane >> 4;        // edge group 0..3
    bool isA = t < 8;
    int beg = offs[v], end = offs[v + 1];
    float adv_v = adv[v];
    float dinv_v = dinv[v];
    float a_l = lrelu02(asv[v] + adv_v);    // self-loop logit
    float m = a_l, s = 1.f;                  // online softmax (self seeds)
    float acc[8];
#pragma unroll
    for (int k = 0; k < 8; k++) acc[k] = 0.f;

    for (int base = beg; base < end; base += 64) {
        int i = base + lane;
        bool has = i < end;
        int2 ew = has ? csr[i] : make_int2(0, 0);
        int u = ew.x;
        float w = __int_as_float(ew.y);
        float a = has ? lrelu02(asv[u] + adv_v) : -3e38f;
        float mc = a;
#pragma unroll
        for (int o = 32; o; o >>= 1) mc = fmaxf(mc, __shfl_xor(mc, o, 64));
        if (mc > m) {
            float r = expf(m - mc);
            s *= r;
            if (isA) {
#pragma unroll
                for (int k = 0; k < 8; k++) acc[k] *= r;
            }
            m = mc;
        }
        float p = has ? expf(a - m) : 0.f;
        float ps = p;
#pragma unroll
        for (int o = 32; o; o >>= 1) ps += __shfl_xor(ps, o, 64);
        s += ps;
        float nrm = has ? (dinv[u] * w * dinv_v) : 0.f;

        int cnt = end - base; if (cnt > 64) cnt = 64;
        int steps = (cnt + 3) >> 2;
        for (int st = 0; st < steps; st++) {
            int idx = st * 4 + g;
            float pj = __shfl(p, idx, 64);
            float nj = __shfl(nrm, idx, 64);
            int   uj = __shfl(u, idx, 64);
            float scale = isA ? pj : nj;
            uint4 d = *(const uint4*)(xp + (size_t)uj * 128 + t * 8);
            unsigned du0 = d.x, du1 = d.y, du2 = d.z, du3 = d.w;
            acc[0] += scale * __uint_as_float(du0 << 16);
            acc[1] += scale * __uint_as_float(du0 & 0xffff0000u);
            acc[2] += scale * __uint_as_float(du1 << 16);
            acc[3] += scale * __uint_as_float(du1 & 0xffff0000u);
            acc[4] += scale * __uint_as_float(du2 << 16);
            acc[5] += scale * __uint_as_float(du2 & 0xffff0000u);
            acc[6] += scale * __uint_as_float(du3 << 16);
            acc[7] += scale * __uint_as_float(du3 & 0xffff0000u);
        }
    }
    // reduce the 4 edge-groups (lanes with equal t hold equal channels)
#pragma unroll
    for (int k = 0; k < 8; k++) {
        acc[k] += __shfl_xor(acc[k], 16, 64);
        acc[k] += __shfl_xor(acc[k], 32, 64);
    }
    // self-loop contribution (uniform across groups)
    {
        uint4 d = *(const uint4*)(xp + (size_t)v * 128 + t * 8);
        float sl = isA ? expf(a_l - m) : (dinv_v * dinv_v);
        unsigned du0 = d.x, du1 = d.y, du2 = d.z, du3 = d.w;
        acc[0] += sl * __uint_as_float(du0 << 16);
        acc[1] += sl * __uint_as_float(du0 & 0xffff0000u);
        acc[2] += sl * __uint_as_float(du1 << 16);
        acc[3] += sl * __uint_as_float(du1 & 0xffff0000u);
        acc[4] += sl * __uint_as_float(du2 << 16);
        acc[5] += sl * __uint_as_float(du2 & 0xffff0000u);
        acc[6] += sl * __uint_as_float(du3 << 16);
        acc[7] += sl * __uint_as_float(du3 & 0xffff0000u);
    }
    // epilogue: normalize/bias/activation; cat index of acc[k] = t*8+k for ALL t
    float inv_s = 1.f / (s + 1e-16f);
    int cbase = t * 8;
#pragma unroll
    for (int k = 0; k < 8; k++) {
        float x;
        if (isA) x = eluf(acc[k] * inv_s + gat_b[cbase + k]);
        else { float c = acc[k] + gcn_b[cbase - 64 + k]; x = c > 0.f ? c : 0.f; }
        acc[k] = x;
    }
    if (g == 0) {
        float4* op = (float4*)(out + (size_t)N + (size_t)v * 128 + cbase);
        op[0] = make_float4(acc[0], acc[1], acc[2], acc[3]);
        op[1] = make_float4(acc[4], acc[5], acc[6], acc[7]);
        float4* lp = (float4*)(&cat_lds[wv][cbase]);
        lp[0] = make_float4(acc[0], acc[1], acc[2], acc[3]);
        lp[1] = make_float4(acc[4], acc[5], acc[6], acc[7]);
    }
    // fuse MLP (same-wave LDS; lane = hidden unit)
    float accf = fb1[lane];
    const float4* wrow = (const float4*)(fw1 + lane * 128);
    const float4* cl = (const float4*)cat_lds[wv];
#pragma unroll 8
    for (int k = 0; k < 32; k++) {
        float4 cv = cl[k];
        float4 w4 = wrow[k];
        accf += cv.x * w4.x + cv.y * w4.y + cv.z * w4.z + cv.w * w4.w;
    }
    float hf = accf > 0.f ? accf : 0.f;
    float p2 = hf * fw2[lane];
#pragma unroll
    for (int o = 32; o; o >>= 1) p2 += __shfl_xor(p2, o, 64);
    if (lane == 0) out[v] = p2 + fb2[0];
}

extern "C" void kernel_launch(void* const* d_in, const int* in_sizes, int n_in,
                              void* d_out, int out_size, void* d_ws, size_t ws_size,
                              hipStream_t stream) {
    const float* x_local  = (const float*)d_in[0];
    const float* x_global = (const float*)d_in[1];
    const float* noise_f  = (const float*)d_in[2];
    const float* coord    = (const float*)d_in[3];
    const int*   ei       = (const int*)d_in[4];
    const float* fc1_w    = (const float*)d_in[5];
    const float* fc1_b    = (const float*)d_in[6];
    const float* fc2_w    = (const float*)d_in[7];
    const float* fc2_b    = (const float*)d_in[8];
    const float* gat_w    = (const float*)d_in[9];
    const float* gat_b    = (const float*)d_in[10];
    const float* att_src  = (const float*)d_in[11];
    const float* att_dst  = (const float*)d_in[12];
    const float* gcn_w    = (const float*)d_in[13];
    const float* gcn_b    = (const float*)d_in[14];
    const float* fuse_w1  = (const float*)d_in[15];
    const float* fuse_b1  = (const float*)d_in[16];
    const float* fuse_w2  = (const float*)d_in[17];
    const float* fuse_b2  = (const float*)d_in[18];
    float* out = (float*)d_out;

    const int N = out_size / 129;        // pred [N] + cat [N,128]
    const int E = in_sizes[4] / 2;

    auto rup = [](size_t b) { return (b + 255) & ~(size_t)255; };
    char* p = (char*)d_ws;
    auto carve = [&](size_t bytes) { char* q = p; p += rup(bytes); return (void*)q; };

    // counts, cursor, deg carved contiguously -> zeroed in one pass
    unsigned int* counts = (unsigned int*)carve((size_t)N * 4);
    unsigned int* cursor = (unsigned int*)carve((size_t)N * 4);
    float* deg   = (float*)carve((size_t)N * 4);                  // -> dinv in place
    int*   offs  = (int*)  carve(((size_t)N + 1) * 4);
    float* asv   = (float*)carve((size_t)N * 4);
    float* adv   = (float*)carve((size_t)N * 4);
    float* wg_e  = (float*)carve((size_t)E * 4);
    int2*  csr   = (int2*) carve((size_t)E * 8);
    bf16*  xp    = (bf16*) carve((size_t)N * 128 * 2);

    dim3 blk(256);
    int NBn = (N + 3) / 4;               // wave-per-node blocks
    int NBe = (E + 255) / 256;           // thread-per-edge blocks
    int bn  = (N + 255) / 256;

    size_t zwords = (rup((size_t)N * 4) * 2 + rup((size_t)N * 4)) / 4;  // counts+cursor+deg
    kzero_u32<<<512, blk, 0, stream>>>(counts, zwords);

    k12<<<NBn + NBe, blk, 0, stream>>>(x_local, x_global, gat_w, gcn_w,
        att_src, att_dst, xp, asv, adv,
        ei, noise_f, coord, fc1_w, fc1_b, fc2_w, fc2_b,
        wg_e, counts, deg, NBn, N, E);

    kscan<<<1, 1024, 0, stream>>>(counts, offs, N);

    kdinv<<<bn, blk, 0, stream>>>(deg, N);

    k2c_scatter<<<NBe, blk, 0, stream>>>(ei, wg_e, offs, cursor, csr, E);

    k3_gather<<<NBn, blk, 0, stream>>>(offs, csr, asv, adv, deg, xp,
        gat_b, gcn_b, fuse_w1, fuse_b1, fuse_w2, fuse_b2, out, N);
}

// Round 8
// 1155.573 us; speedup vs baseline: 1.5605x; 1.0495x over previous
//
#include <hip/hip_runtime.h>
#include <hip/hip_bf16.h>

typedef __hip_bfloat16 bf16;

__device__ __forceinline__ float eluf(float x){ return x > 0.f ? x : (expf(x) - 1.f); }
__device__ __forceinline__ float lrelu02(float x){ return x > 0.f ? x : 0.2f * x; }

// K0: blocks [0, ZB): zero counts+cursor (grid-stride); blocks [ZB, ZB+NBni): per-node noise MLP
__global__ void __launch_bounds__(256) k0_zero_ni(
    unsigned int* __restrict__ zp, size_t zn,
    const float* __restrict__ nf,
    const float* __restrict__ fc1w, const float* __restrict__ fc1b,
    const float* __restrict__ fc2w, const float* __restrict__ fc2b,
    float* __restrict__ ni_arr, int ZB, int N)
{
    int b = (int)blockIdx.x;
    if (b < ZB) {
        size_t i = (size_t)b * blockDim.x + threadIdx.x;
        size_t stride = (size_t)ZB * blockDim.x;
        for (; i < zn; i += stride) zp[i] = 0u;
    } else {
        int n = (b - ZB) * (int)blockDim.x + (int)threadIdx.x;
        if (n >= N) return;
        float f[10];
#pragma unroll
        for (int i = 0; i < 10; i++) f[i] = nf[(size_t)n * 10 + i];
        float ni = fc2b[0];
#pragma unroll
        for (int j = 0; j < 10; j++) {
            float h = fc1b[j];
#pragma unroll
            for (int i = 0; i < 10; i++) h += f[i] * fc1w[j * 10 + i];
            h = eluf(h);
            ni += h * fc2w[j];
        }
        ni_arr[n] = ni;
    }
}

// K12: fused. Blocks [0,NBn): wave/node projections; rest: thread/edge weight (reads ni - safe,
// written by the PREVIOUS launch).
__global__ void __launch_bounds__(256) k12(
    const float* __restrict__ x_local, const float* __restrict__ x_global,
    const float* __restrict__ gat_w, const float* __restrict__ gcn_w,
    const float* __restrict__ att_src, const float* __restrict__ att_dst,
    bf16* __restrict__ xp, float* __restrict__ asv, float* __restrict__ adv,
    const int* __restrict__ ei, const float* __restrict__ coord,
    const float* __restrict__ ni_arr,
    float* __restrict__ wg_e, unsigned int* __restrict__ counts,
    int NBn, int N, int E)
{
    int b = (int)blockIdx.x;
    if (b < NBn) {
        int n = (b * (int)blockDim.x + (int)threadIdx.x) >> 6;
        int lane = threadIdx.x & 63;
        if (n >= N) return;
        float xl = x_local[(size_t)n * 64 + lane];
        float xg = x_global[(size_t)n * 64 + lane];
        float accA = 0.f, accG = 0.f;
        const float* wA = gat_w + lane * 64;
        const float* wG = gcn_w + lane * 64;
#pragma unroll 8
        for (int k = 0; k < 64; k++) {
            float xlk = __shfl(xl, k, 64);
            float xgk = __shfl(xg, k, 64);
            accA += xlk * wA[k];
            accG += xgk * wG[k];
        }
        xp[(size_t)n * 128 + lane]      = __float2bfloat16(accA);
        xp[(size_t)n * 128 + 64 + lane] = __float2bfloat16(accG);
        float va = accA * att_src[lane];
        float vd = accA * att_dst[lane];
#pragma unroll
        for (int o = 32; o; o >>= 1) {
            va += __shfl_xor(va, o, 64);
            vd += __shfl_xor(vd, o, 64);
        }
        if (lane == 0) { asv[n] = va; adv[n] = vd; }
    } else {
        int e = (b - NBn) * (int)blockDim.x + (int)threadIdx.x;
        if (e >= E) return;
        int u = ei[e], v = ei[E + e];
        float2 cu = *(const float2*)(coord + (size_t)u * 2);
        float2 cv = *(const float2*)(coord + (size_t)v * 2);
        float niu = ni_arr[u];
        float dx = cu.x - cv.x, dy = cu.y - cv.y;
        float gw = expf(-(dx * dx + dy * dy) * (1.0f / 1800.0f));
        float x = gw * (1.f + niu);
        float w = 0.1f + 1.9f / (1.f + expf(1.f - x));
        w = (w >= 0.2f) ? w : 0.f;
        wg_e[e] = w;
        if (w > 0.f) atomicAdd(&counts[v], 1u);
    }
}

// Kscan: single-block exclusive scan, 4 elements/thread
__global__ void __launch_bounds__(1024) kscan(
    const unsigned int* __restrict__ counts, int* __restrict__ offs, int N)
{
    __shared__ int wsum[16];
    int tid = threadIdx.x;
    int lane = tid & 63, wv = tid >> 6;
    int carry = 0;
    for (int base = 0; base < N; base += 4096) {
        int i0 = base + tid * 4;
        uint4 c = make_uint4(0u, 0u, 0u, 0u);
        if (i0 + 3 < N) c = *(const uint4*)(counts + i0);
        else {
            if (i0 + 0 < N) c.x = counts[i0];
            if (i0 + 1 < N) c.y = counts[i0 + 1];
            if (i0 + 2 < N) c.z = counts[i0 + 2];
            if (i0 + 3 < N) c.w = counts[i0 + 3];
        }
        int t0 = (int)c.x, t1 = t0 + (int)c.y, t2 = t1 + (int)c.z, tot = t2 + (int)c.w;
        int incl = tot;
#pragma unroll
        for (int o = 1; o < 64; o <<= 1) {
            int tt = __shfl_up(incl, o, 64);
            if (lane >= o) incl += tt;
        }
        if (lane == 63) wsum[wv] = incl;
        __syncthreads();
        if (wv == 0 && lane < 16) {
            int s2 = wsum[lane];
#pragma unroll
            for (int o = 1; o < 16; o <<= 1) {
                int tt = __shfl_up(s2, o, 16);
                if (lane >= o) s2 += tt;
            }
            wsum[lane] = s2;
        }
        __syncthreads();
        int wpre = (wv > 0) ? wsum[wv - 1] : 0;
        int excl = carry + wpre + (incl - tot);
        int4 o4 = make_int4(excl, excl + t0, excl + t1, excl + t2);
        if (i0 + 3 < N) *(int4*)(offs + i0) = o4;
        else {
            if (i0 + 0 < N) offs[i0]     = o4.x;
            if (i0 + 1 < N) offs[i0 + 1] = o4.y;
            if (i0 + 2 < N) offs[i0 + 2] = o4.z;
            if (i0 + 3 < N) offs[i0 + 3] = o4.w;
        }
        carry += wsum[15];
        __syncthreads();
    }
    if (tid == 0) offs[N] = carry;
}

// K2c: scatter valid edges (u, w) into dst-CSR slots
__global__ void __launch_bounds__(256) k2c_scatter(
    const int* __restrict__ ei, const float* __restrict__ wg_e,
    const int* __restrict__ offs, unsigned int* __restrict__ cursor,
    int2* __restrict__ csr, int E)
{
    int e = blockIdx.x * blockDim.x + threadIdx.x;
    if (e >= E) return;
    float w = wg_e[e];
    if (w <= 0.f) return;
    int u = ei[e], v = ei[E + e];
    int pos = offs[v] + (int)atomicAdd(&cursor[v], 1u);
    int2 val;
    val.x = u;
    val.y = __float_as_int(w);
    csr[pos] = val;
}

// Kdeg: thread/node; deg[v] = 1 + sum of w over CSR row -> dinv (no atomics)
__global__ void __launch_bounds__(256) kdeg(
    const int* __restrict__ offs, const int2* __restrict__ csr,
    float* __restrict__ dinv, int N)
{
    int n = blockIdx.x * blockDim.x + threadIdx.x;
    if (n >= N) return;
    int beg = offs[n], end = offs[n + 1];
    float d = 1.0f;                    // self-loop
    for (int i = beg; i < end; i++) d += __int_as_float(csr[i].y);
    dinv[n] = rsqrtf(d);
}

// K3: wave per dst node. 16 lanes/edge, 16B xp loads, 4 edges/step.
__global__ void __launch_bounds__(256) k3_gather(
    const int* __restrict__ offs, const int2* __restrict__ csr,
    const float* __restrict__ asv, const float* __restrict__ adv,
    const float* __restrict__ dinv, const bf16* __restrict__ xp,
    const float* __restrict__ gat_b, const float* __restrict__ gcn_b,
    const float* __restrict__ fw1, const float* __restrict__ fb1,
    const float* __restrict__ fw2, const float* __restrict__ fb2,
    float* __restrict__ out, int N)
{
    __shared__ float cat_lds[4][128];
    int wv = threadIdx.x >> 6;
    int lane = threadIdx.x & 63;
    int v = blockIdx.x * 4 + wv;
    if (v >= N) return;

    int t = lane & 15;        // 16B-slot within row (t<8: GAT chans, t>=8: GCN)
    int g = lane >> 4;        // edge group 0..3
    bool isA = t < 8;
    int beg = offs[v], end = offs[v + 1];
    float adv_v = adv[v];
    float dinv_v = dinv[v];
    float a_l = lrelu02(asv[v] + adv_v);    // self-loop logit
    float m = a_l, s = 1.f;                  // online softmax (self seeds)
    float acc[8];
#pragma unroll
    for (int k = 0; k < 8; k++) acc[k] = 0.f;

    for (int base = beg; base < end; base += 64) {
        int i = base + lane;
        bool has = i < end;
        int2 ew = has ? csr[i] : make_int2(0, 0);
        int u = ew.x;
        float w = __int_as_float(ew.y);
        float a = has ? lrelu02(asv[u] + adv_v) : -3e38f;
        float mc = a;
#pragma unroll
        for (int o = 32; o; o >>= 1) mc = fmaxf(mc, __shfl_xor(mc, o, 64));
        if (mc > m) {
            float r = expf(m - mc);
            s *= r;
            if (isA) {
#pragma unroll
                for (int k = 0; k < 8; k++) acc[k] *= r;
            }
            m = mc;
        }
        float p = has ? expf(a - m) : 0.f;
        float ps = p;
#pragma unroll
        for (int o = 32; o; o >>= 1) ps += __shfl_xor(ps, o, 64);
        s += ps;
        float nrm = has ? (dinv[u] * w * dinv_v) : 0.f;

        int cnt = end - base; if (cnt > 64) cnt = 64;
        int steps = (cnt + 3) >> 2;
        for (int st = 0; st < steps; st++) {
            int idx = st * 4 + g;
            float pj = __shfl(p, idx, 64);
            float nj = __shfl(nrm, idx, 64);
            int   uj = __shfl(u, idx, 64);
            float scale = isA ? pj : nj;
            uint4 d = *(const uint4*)(xp + (size_t)uj * 128 + t * 8);
            unsigned du0 = d.x, du1 = d.y, du2 = d.z, du3 = d.w;
            acc[0] += scale * __uint_as_float(du0 << 16);
            acc[1] += scale * __uint_as_float(du0 & 0xffff0000u);
            acc[2] += scale * __uint_as_float(du1 << 16);
            acc[3] += scale * __uint_as_float(du1 & 0xffff0000u);
            acc[4] += scale * __uint_as_float(du2 << 16);
            acc[5] += scale * __uint_as_float(du2 & 0xffff0000u);
            acc[6] += scale * __uint_as_float(du3 << 16);
            acc[7] += scale * __uint_as_float(du3 & 0xffff0000u);
        }
    }
    // reduce the 4 edge-groups
#pragma unroll
    for (int k = 0; k < 8; k++) {
        acc[k] += __shfl_xor(acc[k], 16, 64);
        acc[k] += __shfl_xor(acc[k], 32, 64);
    }
    // self-loop contribution
    {
        uint4 d = *(const uint4*)(xp + (size_t)v * 128 + t * 8);
        float sl = isA ? expf(a_l - m) : (dinv_v * dinv_v);
        unsigned du0 = d.x, du1 = d.y, du2 = d.z, du3 = d.w;
        acc[0] += sl * __uint_as_float(du0 << 16);
        acc[1] += sl * __uint_as_float(du0 & 0xffff0000u);
        acc[2] += sl * __uint_as_float(du1 << 16);
        acc[3] += sl * __uint_as_float(du1 & 0xffff0000u);
        acc[4] += sl * __uint_as_float(du2 << 16);
        acc[5] += sl * __uint_as_float(du2 & 0xffff0000u);
        acc[6] += sl * __uint_as_float(du3 << 16);
        acc[7] += sl * __uint_as_float(du3 & 0xffff0000u);
    }
    // epilogue
    float inv_s = 1.f / (s + 1e-16f);
    int cbase = t * 8;
#pragma unroll
    for (int k = 0; k < 8; k++) {
        float x;
        if (isA) x = eluf(acc[k] * inv_s + gat_b[cbase + k]);
        else { float c = acc[k] + gcn_b[cbase - 64 + k]; x = c > 0.f ? c : 0.f; }
        acc[k] = x;
    }
    if (g == 0) {
        float4* op = (float4*)(out + (size_t)N + (size_t)v * 128 + cbase);
        op[0] = make_float4(acc[0], acc[1], acc[2], acc[3]);
        op[1] = make_float4(acc[4], acc[5], acc[6], acc[7]);
        float4* lp = (float4*)(&cat_lds[wv][cbase]);
        lp[0] = make_float4(acc[0], acc[1], acc[2], acc[3]);
        lp[1] = make_float4(acc[4], acc[5], acc[6], acc[7]);
    }
    // fuse MLP
    float accf = fb1[lane];
    const float4* wrow = (const float4*)(fw1 + lane * 128);
    const float4* cl = (const float4*)cat_lds[wv];
#pragma unroll 8
    for (int k = 0; k < 32; k++) {
        float4 cv = cl[k];
        float4 w4 = wrow[k];
        accf += cv.x * w4.x + cv.y * w4.y + cv.z * w4.z + cv.w * w4.w;
    }
    float hf = accf > 0.f ? accf : 0.f;
    float p2 = hf * fw2[lane];
#pragma unroll
    for (int o = 32; o; o >>= 1) p2 += __shfl_xor(p2, o, 64);
    if (lane == 0) out[v] = p2 + fb2[0];
}

extern "C" void kernel_launch(void* const* d_in, const int* in_sizes, int n_in,
                              void* d_out, int out_size, void* d_ws, size_t ws_size,
                              hipStream_t stream) {
    const float* x_local  = (const float*)d_in[0];
    const float* x_global = (const float*)d_in[1];
    const float* noise_f  = (const float*)d_in[2];
    const float* coord    = (const float*)d_in[3];
    const int*   ei       = (const int*)d_in[4];
    const float* fc1_w    = (const float*)d_in[5];
    const float* fc1_b    = (const float*)d_in[6];
    const float* fc2_w    = (const float*)d_in[7];
    const float* fc2_b    = (const float*)d_in[8];
    const float* gat_w    = (const float*)d_in[9];
    const float* gat_b    = (const float*)d_in[10];
    const float* att_src  = (const float*)d_in[11];
    const float* att_dst  = (const float*)d_in[12];
    const float* gcn_w    = (const float*)d_in[13];
    const float* gcn_b    = (const float*)d_in[14];
    const float* fuse_w1  = (const float*)d_in[15];
    const float* fuse_b1  = (const float*)d_in[16];
    const float* fuse_w2  = (const float*)d_in[17];
    const float* fuse_b2  = (const float*)d_in[18];
    float* out = (float*)d_out;

    const int N = out_size / 129;        // pred [N] + cat [N,128]
    const int E = in_sizes[4] / 2;

    auto rup = [](size_t b) { return (b + 255) & ~(size_t)255; };
    char* p = (char*)d_ws;
    auto carve = [&](size_t bytes) { char* q = p; p += rup(bytes); return (void*)q; };

    // counts + cursor contiguous -> zeroed in one pass
    unsigned int* counts = (unsigned int*)carve((size_t)N * 4);
    unsigned int* cursor = (unsigned int*)carve((size_t)N * 4);
    float* dinv  = (float*)carve((size_t)N * 4);
    int*   offs  = (int*)  carve(((size_t)N + 1) * 4);
    float* asv   = (float*)carve((size_t)N * 4);
    float* adv   = (float*)carve((size_t)N * 4);
    float* ni    = (float*)carve((size_t)N * 4);
    float* wg_e  = (float*)carve((size_t)E * 4);
    int2*  csr   = (int2*) carve((size_t)E * 8);
    bf16*  xp    = (bf16*) carve((size_t)N * 128 * 2);

    dim3 blk(256);
    int NBn  = (N + 3) / 4;              // wave-per-node blocks
    int NBni = (N + 255) / 256;          // thread-per-node blocks
    int NBe  = (E + 255) / 256;          // thread-per-edge blocks
    int bn   = (N + 255) / 256;
    int ZB   = 256;                      // zeroing blocks in k0

    k0_zero_ni<<<ZB + NBni, blk, 0, stream>>>(counts, (rup((size_t)N * 4) * 2) / 4,
        noise_f, fc1_w, fc1_b, fc2_w, fc2_b, ni, ZB, N);

    k12<<<NBn + NBe, blk, 0, stream>>>(x_local, x_global, gat_w, gcn_w,
        att_src, att_dst, xp, asv, adv,
        ei, coord, ni, wg_e, counts, NBn, N, E);

    kscan<<<1, 1024, 0, stream>>>(counts, offs, N);

    k2c_scatter<<<NBe, blk, 0, stream>>>(ei, wg_e, offs, cursor, csr, E);

    kdeg<<<bn, blk, 0, stream>>>(offs, csr, dinv, N);

    k3_gather<<<NBn, blk, 0, stream>>>(offs, csr, asv, adv, dinv, xp,
        gat_b, gcn_b, fuse_w1, fuse_b1, fuse_w2, fuse_b2, out, N);
}